// Round 14
// baseline (36.985 us; speedup 1.0000x reference)
//
#include <hip/hip_runtime.h>

#define DD 128   // feature dim, fixed by the reference

typedef float v2f __attribute__((ext_vector_type(2)));
typedef float v4f __attribute__((ext_vector_type(4)));

// Packed per-pair update: z = x*a + c; zz = z*z; p *= (1 - zz); s += zz.
#define UPD2(P, S, XX, AA, CC)                                   \
    {                                                            \
        v2f z  = __builtin_elementwise_fma((XX), (AA), (CC));    \
        v2f zz = z * z;                                          \
        P = __builtin_elementwise_fma(-zz, P, P);                \
        S += zz;                                                 \
    }

// Register-resident a/c structure -- NO LDS, NO barriers, NO staging.
//   lane = (dq<<4) | ncol : ncol picks one of 16 n-rows, dq one of four
//   32-d chunks. Each thread keeps a = 1/scale, c = -bias/scale for its
//   (n-row, d-chunk) in 64 VGPRs, loaded ONCE. The inner loop has only
//   per-lane VMEM x loads (vmcnt domain; 4 coalesced 16B segments/instr)
//   and pk-FMA math -- removes the ds_read/s_load lgkmcnt-mixing
//   serialization that R1-R13 all carried.
//   Per b-row: each thread folds its 32-d chunk (window = R11's proven
//   numerics, safer order (p.x*e)*p.y), then the 4 dq partials combine
//   multiplicatively via two __shfl_xor (exact decomposition; partials
//   are true sub-products <= 1 after their own Gaussian fold).
// Wave covers 16 n x 128 d per b-row; 8 b-rows per wave; block = 8 waves.
// Grid (N/16, B/64) = (32, 32) = 1024 blocks -> 4 waves/SIMD at ~100 VGPR.
__global__ __launch_bounds__(512, 4)
void wavelet_prod_kernel(const float* __restrict__ x,
                         const float* __restrict__ bias,
                         const float* __restrict__ scale,
                         float* __restrict__ out,
                         int B, int N)
{
    const int tid  = threadIdx.x;
    const int lane = tid & 63;
    const int wave = tid >> 6;
    const int ncol = lane & 15;       // n-column within the block's 16-n tile
    const int dq   = lane >> 4;       // 32-d chunk selector (0..3)

    const int n0 = blockIdx.x * 16;             // 16 n per block
    const int bb = blockIdx.y * 64 + wave * 8;  // this wave's 8 b-rows

    // ---- one-time: a/c for (row n0+ncol, d in [dq*32, dq*32+32)) -> regs ----
    const v4f* s4 = (const v4f*)(scale + (size_t)(n0 + ncol) * DD + dq * 32);
    const v4f* b4 = (const v4f*)(bias  + (size_t)(n0 + ncol) * DD + dq * 32);
    v4f a_r[8], c_r[8];               // compile-time indexed only (rule #20)
    #pragma unroll
    for (int j = 0; j < 8; ++j) {
        v4f sv = s4[j];
        v4f bv = b4[j];
        v4f av;
        av.x = __builtin_amdgcn_rcpf(sv.x);
        av.y = __builtin_amdgcn_rcpf(sv.y);
        av.z = __builtin_amdgcn_rcpf(sv.z);
        av.w = __builtin_amdgcn_rcpf(sv.w);
        a_r[j] = av;
        c_r[j] = -bv * av;
    }

    const float kexp = -0.7213475204444817f;  // -0.5 * log2(e)
    const float* xbase = x + (size_t)bb * DD + dq * 32;

    #pragma unroll 2
    for (int r = 0; r < 8; ++r) {
        const v4f* xb = (const v4f*)(xbase + r * DD);
        v2f p = {1.f, 1.f};
        v2f s = {0.f, 0.f};
        #pragma unroll
        for (int j = 0; j < 8; ++j) { // 32 d: 16 packed factors per chain
            v4f xv = xb[j];
            UPD2(p, s, xv.lo, a_r[j].lo, c_r[j].lo);
            UPD2(p, s, xv.hi, a_r[j].hi, c_r[j].hi);
        }
        // Gaussian fold for this chunk, then merge chains (overflow-safe order)
        float e  = __builtin_amdgcn_exp2f((s.x + s.y) * kexp);
        float pp = (p.x * e) * p.y;   // true 32-d sub-product, |pp| <= 1
        // combine the 4 dq partials: butterfly product across lane groups
        pp *= __shfl_xor(pp, 16, 64);
        pp *= __shfl_xor(pp, 32, 64);
        if (dq == 0)
            out[(size_t)(bb + r) * N + n0 + ncol] = pp;
    }
}

extern "C" void kernel_launch(void* const* d_in, const int* in_sizes, int n_in,
                              void* d_out, int out_size, void* d_ws, size_t ws_size,
                              hipStream_t stream)
{
    const float* x     = (const float*)d_in[0];
    const float* bias  = (const float*)d_in[1];
    const float* scale = (const float*)d_in[2];
    float* out = (float*)d_out;

    const int B = in_sizes[0] / DD;   // 2048
    const int N = in_sizes[1] / DD;   // 512

    dim3 grid(N / 16, B / 64);        // (32, 32) = 1024 blocks
    wavelet_prod_kernel<<<grid, 512, 0, stream>>>(x, bias, scale, out, B, N);
}

// Round 15
// 25.354 us; speedup vs baseline: 1.4588x; 1.4588x over previous
//
#include <hip/hip_runtime.h>

#define DD 128   // feature dim, fixed by the reference

typedef float v2f __attribute__((ext_vector_type(2)));
typedef float v4f __attribute__((ext_vector_type(4)));
typedef float v8f __attribute__((ext_vector_type(8)));

// Packed per-pair update: z = x*a + c; zz = z*z; p *= (1 - zz); s += zz.
#define UPD2(P, S, XX, AA, CC)                                   \
    {                                                            \
        v2f z  = __builtin_elementwise_fma((XX), (AA), (CC));    \
        v2f zz = z * z;                                          \
        P = __builtin_elementwise_fma(-zz, P, P);                \
        S += zz;                                                 \
    }

// One row's update for a quad-pair (8 d) against a0/c0, a1/c1.
#define UPD8(P, S, XV)                                           \
    {                                                            \
        UPD2(P, S, (XV).lo.lo, a0.lo, c0.lo);                    \
        UPD2(P, S, (XV).lo.hi, a0.hi, c0.hi);                    \
        UPD2(P, S, (XV).hi.lo, a1.lo, c1.lo);                    \
        UPD2(P, S, (XV).hi.hi, a1.hi, c1.hi);                    \
    }

// R11 structure (18.07 us) with ONE change: x loads moved from SMEM
// (s_load_dwordx8, ~3-4 in flight at the 112-SGPR budget -> exposed 200-300cy
// latency every ~16 pk instrs, sharing lgkmcnt with the ds_reads) to VMEM
// (global_load via a formally-divergent base: opaque zero from inline asm).
// Wave-uniform addresses -> coalescer broadcast; vmcnt domain decouples x
// waits from a/c ds_reads; deep VMEM queue hides latency.
//
// Tile: 64 n (one per lane) x 64 b (8 rows per thread, wave-uniform) per block.
// LDS: a = 1/scale, c = -bias/scale as [64 rows][32 quads] v4f (64 KB),
//   quad slot XOR-swizzled by (row&7); compute reads arow[q ^ (lane&7)] = quad q
//   of row=lane (slot q^s holds quad (q^s)^s = q -- pairing verified).
// Fold-32 numerics identical to R11 (16 factors/chain, bounded partials).
// ~95 live regs, no arrays, no manual prefetch (R7/R8 spill lesson).
__global__ __launch_bounds__(512, 4)
void wavelet_prod_kernel(const float* __restrict__ x,
                         const float* __restrict__ bias,
                         const float* __restrict__ scale,
                         float* __restrict__ out,
                         int B, int N)
{
    __shared__ v4f a_s[64 * 32];
    __shared__ v4f c_s[64 * 32];

    const int tid  = threadIdx.x;
    const int lane = tid & 63;
    const int wave = tid >> 6;

    const int n0 = blockIdx.x * 64;   // 64 n per block
    const int bb = blockIdx.y * 64;   // 64 b per block (8 per wave/thread)

    // ---- one-time staging: 64 x 128 bias/scale tile -> a,c in LDS ----
    {
        const v4f* b4 = (const v4f*)(bias  + (size_t)n0 * DD);
        const v4f* s4 = (const v4f*)(scale + (size_t)n0 * DD);
        #pragma unroll
        for (int k = 0; k < 4; ++k) {
            int flat = tid + k * 512;          // 0..2047 v4f slots
            int r = flat >> 5;                 // row within tile (0..63)
            int q = flat & 31;                 // d-quad (0..31)
            v4f sv = s4[flat];
            v4f bv = b4[flat];
            v4f av, cv;
            av.x = __builtin_amdgcn_rcpf(sv.x);
            av.y = __builtin_amdgcn_rcpf(sv.y);
            av.z = __builtin_amdgcn_rcpf(sv.z);
            av.w = __builtin_amdgcn_rcpf(sv.w);
            cv = -bv * av;
            int dst = r * 32 + (q ^ (r & 7));
            a_s[dst] = av;
            c_s[dst] = cv;
        }
    }
    __syncthreads();

    const int b0 = bb + wave * 8;     // wave's 8 b-rows (uniform, but loads VMEM)

    // Opaque zero in a VGPR: compiler can't prove it constant, so the x base
    // is "divergent" -> global_load (VMEM/vmcnt) instead of s_load (SMEM/lgkm).
    unsigned zoff;
    asm("v_mov_b32 %0, 0" : "=v"(zoff));
    const v8f* xr8 = (const v8f*)((const char*)(x + (size_t)b0 * DD) + zoff);

    const v4f* arow = a_s + lane * 32;
    const v4f* crow = c_s + lane * 32;
    const int sw = lane & 7;

    // Two packed chains per row, merged at each 32-d fold (16 factors/chain).
    v2f p0 = {1.f, 1.f}, p1 = {1.f, 1.f}, p2 = {1.f, 1.f}, p3 = {1.f, 1.f};
    v2f p4 = {1.f, 1.f}, p5 = {1.f, 1.f}, p6 = {1.f, 1.f}, p7 = {1.f, 1.f};
    v2f s0 = {0.f, 0.f}, s1 = {0.f, 0.f}, s2 = {0.f, 0.f}, s3 = {0.f, 0.f};
    v2f s4v = {0.f, 0.f}, s5 = {0.f, 0.f}, s6 = {0.f, 0.f}, s7 = {0.f, 0.f};

    const float kexp = -0.7213475204444817f;  // -0.5 * log2(e)

    #pragma unroll
    for (int w = 0; w < 4; ++w) {             // 4 folds of 32 d
        #pragma unroll
        for (int h = 0; h < 4; ++h) {         // 4 quad-pairs per fold window
            const int q0 = w * 8 + h * 2;     // quads q0, q0+1
            const int sl0 = q0 ^ sw;
            const int sl1 = (q0 + 1) ^ sw;
            v4f a0 = arow[sl0], c0 = crow[sl0];
            v4f a1 = arow[sl1], c1 = crow[sl1];
            const int xi = w * 4 + h;         // v8f index within row
            // rows in two groups of 4: <=4 v8f of x in flight
            {
                v8f xA0 = xr8[0 * 16 + xi];
                v8f xA1 = xr8[1 * 16 + xi];
                v8f xA2 = xr8[2 * 16 + xi];
                v8f xA3 = xr8[3 * 16 + xi];
                UPD8(p0, s0, xA0);
                UPD8(p1, s1, xA1);
                UPD8(p2, s2, xA2);
                UPD8(p3, s3, xA3);
            }
            {
                v8f xB0 = xr8[4 * 16 + xi];
                v8f xB1 = xr8[5 * 16 + xi];
                v8f xB2 = xr8[6 * 16 + xi];
                v8f xB3 = xr8[7 * 16 + xi];
                UPD8(p4, s4v, xB0);
                UPD8(p5, s5, xB1);
                UPD8(p6, s6, xB2);
                UPD8(p7, s7, xB3);
            }
        }
        // fold Gaussian factor + merge packed chains every 32 d
        p0.x = p0.x * p0.y * __builtin_amdgcn_exp2f((s0.x + s0.y) * kexp);
        p0.y = 1.f; s0 = (v2f){0.f, 0.f};
        p1.x = p1.x * p1.y * __builtin_amdgcn_exp2f((s1.x + s1.y) * kexp);
        p1.y = 1.f; s1 = (v2f){0.f, 0.f};
        p2.x = p2.x * p2.y * __builtin_amdgcn_exp2f((s2.x + s2.y) * kexp);
        p2.y = 1.f; s2 = (v2f){0.f, 0.f};
        p3.x = p3.x * p3.y * __builtin_amdgcn_exp2f((s3.x + s3.y) * kexp);
        p3.y = 1.f; s3 = (v2f){0.f, 0.f};
        p4.x = p4.x * p4.y * __builtin_amdgcn_exp2f((s4v.x + s4v.y) * kexp);
        p4.y = 1.f; s4v = (v2f){0.f, 0.f};
        p5.x = p5.x * p5.y * __builtin_amdgcn_exp2f((s5.x + s5.y) * kexp);
        p5.y = 1.f; s5 = (v2f){0.f, 0.f};
        p6.x = p6.x * p6.y * __builtin_amdgcn_exp2f((s6.x + s6.y) * kexp);
        p6.y = 1.f; s6 = (v2f){0.f, 0.f};
        p7.x = p7.x * p7.y * __builtin_amdgcn_exp2f((s7.x + s7.y) * kexp);
        p7.y = 1.f; s7 = (v2f){0.f, 0.f};
    }

    float* o = out + (size_t)b0 * N + n0 + lane;
    o[0 * N] = p0.x;
    o[1 * N] = p1.x;
    o[2 * N] = p2.x;
    o[3 * N] = p3.x;
    o[4 * N] = p4.x;
    o[5 * N] = p5.x;
    o[6 * N] = p6.x;
    o[7 * N] = p7.x;
}

extern "C" void kernel_launch(void* const* d_in, const int* in_sizes, int n_in,
                              void* d_out, int out_size, void* d_ws, size_t ws_size,
                              hipStream_t stream)
{
    const float* x     = (const float*)d_in[0];
    const float* bias  = (const float*)d_in[1];
    const float* scale = (const float*)d_in[2];
    float* out = (float*)d_out;

    const int B = in_sizes[0] / DD;   // 2048
    const int N = in_sizes[1] / DD;   // 512

    dim3 grid(N / 64, B / 64);        // (8, 32) = 256 blocks = 1 per CU
    wavelet_prod_kernel<<<grid, 512, 0, stream>>>(x, bias, scale, out, B, N);
}

// Round 16
// 17.621 us; speedup vs baseline: 2.0990x; 1.4389x over previous
//
#include <hip/hip_runtime.h>

#define DD 128   // feature dim, fixed by the reference

typedef float v2f  __attribute__((ext_vector_type(2)));
typedef float v4f  __attribute__((ext_vector_type(4)));
typedef float v8f  __attribute__((ext_vector_type(8)));
typedef float v16f __attribute__((ext_vector_type(16)));

// Packed per-pair update: z = x*a + c; zz = z*z; p *= (1 - zz); s += zz.
#define UPD2(P, S, XX, AA, CC)                                   \
    {                                                            \
        v2f z  = __builtin_elementwise_fma((XX), (AA), (CC));    \
        v2f zz = z * z;                                          \
        P = __builtin_elementwise_fma(-zz, P, P);                \
        S += zz;                                                 \
    }

// One row's update for a quad-pair (8 d) against a0/c0, a1/c1.
#define UPD8(P, S, XV)                                           \
    {                                                            \
        UPD2(P, S, (XV).lo.lo, a0.lo, c0.lo);                    \
        UPD2(P, S, (XV).lo.hi, a0.hi, c0.hi);                    \
        UPD2(P, S, (XV).hi.lo, a1.lo, c1.lo);                    \
        UPD2(P, S, (XV).hi.hi, a1.hi, c1.hi);                    \
    }

// R11 structure (18.07 us) with ONE change: x rows loaded as wave-uniform
// v16f (s_load_dwordx16, 64 B) -- 64 instead of 128 SMEM instructions per
// wave, half the s_waitcnt interlock points. Same trick that won R11
// (dwordx4 -> dwordx8). Everything else byte-identical to R11.
//
// Tile: 64 n (one per lane) x 64 b (8 rows per thread, wave-uniform) per block.
// LDS: a = 1/scale, c = -bias/scale as [64 rows][32 quads] v4f (64 KB),
//   quad slot XOR-swizzled by (row&7); compute reads arow[q ^ (lane&7)] = quad q
//   of row=lane (slot q^s holds quad (q^s)^s = q -- pairing verified).
// Fold-32 numerics identical to R11 (16 factors/chain, bounded partials).
// No arrays, no manual prefetch (R7/R8 spill lesson).
__global__ __launch_bounds__(512, 4)
void wavelet_prod_kernel(const float* __restrict__ x,
                         const float* __restrict__ bias,
                         const float* __restrict__ scale,
                         float* __restrict__ out,
                         int B, int N)
{
    __shared__ v4f a_s[64 * 32];
    __shared__ v4f c_s[64 * 32];

    const int tid  = threadIdx.x;
    const int lane = tid & 63;
    const int wave = tid >> 6;

    const int n0 = blockIdx.x * 64;   // 64 n per block
    const int bb = blockIdx.y * 64;   // 64 b per block (8 per wave/thread)

    // ---- one-time staging: 64 x 128 bias/scale tile -> a,c in LDS ----
    {
        const v4f* b4 = (const v4f*)(bias  + (size_t)n0 * DD);
        const v4f* s4 = (const v4f*)(scale + (size_t)n0 * DD);
        #pragma unroll
        for (int k = 0; k < 4; ++k) {
            int flat = tid + k * 512;          // 0..2047 v4f slots
            int r = flat >> 5;                 // row within tile (0..63)
            int q = flat & 31;                 // d-quad (0..31)
            v4f sv = s4[flat];
            v4f bv = b4[flat];
            v4f av, cv;
            av.x = __builtin_amdgcn_rcpf(sv.x);
            av.y = __builtin_amdgcn_rcpf(sv.y);
            av.z = __builtin_amdgcn_rcpf(sv.z);
            av.w = __builtin_amdgcn_rcpf(sv.w);
            cv = -bv * av;
            int dst = r * 32 + (q ^ (r & 7));
            a_s[dst] = av;
            c_s[dst] = cv;
        }
    }
    __syncthreads();

    const int b0 = __builtin_amdgcn_readfirstlane(bb + wave * 8);
    const v16f* xr16 = (const v16f*)(x + (size_t)b0 * DD);  // rows stride 8 v16f

    const v4f* arow = a_s + lane * 32;
    const v4f* crow = c_s + lane * 32;
    const int sw = lane & 7;

    // Two packed chains per row, merged at each 32-d fold (16 factors/chain).
    v2f p0 = {1.f, 1.f}, p1 = {1.f, 1.f}, p2 = {1.f, 1.f}, p3 = {1.f, 1.f};
    v2f p4 = {1.f, 1.f}, p5 = {1.f, 1.f}, p6 = {1.f, 1.f}, p7 = {1.f, 1.f};
    v2f s0 = {0.f, 0.f}, s1 = {0.f, 0.f}, s2 = {0.f, 0.f}, s3 = {0.f, 0.f};
    v2f s4v = {0.f, 0.f}, s5 = {0.f, 0.f}, s6 = {0.f, 0.f}, s7 = {0.f, 0.f};

    const float kexp = -0.7213475204444817f;  // -0.5 * log2(e)

    #pragma unroll
    for (int w = 0; w < 4; ++w) {             // 4 folds of 32 d
        #pragma unroll
        for (int g = 0; g < 2; ++g) {         // 2 x 16-d half-windows
            // quads q0..q0+3 of this half-window; one v16f of x per row
            const int q0  = w * 8 + g * 4;
            const int xi  = w * 2 + g;        // v16f index within row
            const int slA0 = (q0 + 0) ^ sw;
            const int slA1 = (q0 + 1) ^ sw;
            const int slB0 = (q0 + 2) ^ sw;
            const int slB1 = (q0 + 3) ^ sw;
            // first quad-pair regs
            {
                v4f a0 = arow[slA0], c0 = crow[slA0];
                v4f a1 = arow[slA1], c1 = crow[slA1];
                v16f xA0 = xr16[0 * 8 + xi];
                v16f xA1 = xr16[1 * 8 + xi];
                v16f xA2 = xr16[2 * 8 + xi];
                v16f xA3 = xr16[3 * 8 + xi];
                UPD8(p0, s0, xA0.lo);
                UPD8(p1, s1, xA1.lo);
                UPD8(p2, s2, xA2.lo);
                UPD8(p3, s3, xA3.lo);
                v4f a0b = arow[slB0], c0b = crow[slB0];
                v4f a1b = arow[slB1], c1b = crow[slB1];
                {
                    v4f a0 = a0b, c0 = c0b, a1 = a1b, c1 = c1b;
                    UPD8(p0, s0, xA0.hi);
                    UPD8(p1, s1, xA1.hi);
                    UPD8(p2, s2, xA2.hi);
                    UPD8(p3, s3, xA3.hi);
                }
                v16f xB0 = xr16[4 * 8 + xi];
                v16f xB1 = xr16[5 * 8 + xi];
                v16f xB2 = xr16[6 * 8 + xi];
                v16f xB3 = xr16[7 * 8 + xi];
                UPD8(p4, s4v, xB0.lo);
                UPD8(p5, s5,  xB1.lo);
                UPD8(p6, s6,  xB2.lo);
                UPD8(p7, s7,  xB3.lo);
                {
                    v4f a0 = a0b, c0 = c0b, a1 = a1b, c1 = c1b;
                    UPD8(p4, s4v, xB0.hi);
                    UPD8(p5, s5,  xB1.hi);
                    UPD8(p6, s6,  xB2.hi);
                    UPD8(p7, s7,  xB3.hi);
                }
            }
        }
        // fold Gaussian factor + merge packed chains every 32 d
        p0.x = p0.x * p0.y * __builtin_amdgcn_exp2f((s0.x + s0.y) * kexp);
        p0.y = 1.f; s0 = (v2f){0.f, 0.f};
        p1.x = p1.x * p1.y * __builtin_amdgcn_exp2f((s1.x + s1.y) * kexp);
        p1.y = 1.f; s1 = (v2f){0.f, 0.f};
        p2.x = p2.x * p2.y * __builtin_amdgcn_exp2f((s2.x + s2.y) * kexp);
        p2.y = 1.f; s2 = (v2f){0.f, 0.f};
        p3.x = p3.x * p3.y * __builtin_amdgcn_exp2f((s3.x + s3.y) * kexp);
        p3.y = 1.f; s3 = (v2f){0.f, 0.f};
        p4.x = p4.x * p4.y * __builtin_amdgcn_exp2f((s4v.x + s4v.y) * kexp);
        p4.y = 1.f; s4v = (v2f){0.f, 0.f};
        p5.x = p5.x * p5.y * __builtin_amdgcn_exp2f((s5.x + s5.y) * kexp);
        p5.y = 1.f; s5 = (v2f){0.f, 0.f};
        p6.x = p6.x * p6.y * __builtin_amdgcn_exp2f((s6.x + s6.y) * kexp);
        p6.y = 1.f; s6 = (v2f){0.f, 0.f};
        p7.x = p7.x * p7.y * __builtin_amdgcn_exp2f((s7.x + s7.y) * kexp);
        p7.y = 1.f; s7 = (v2f){0.f, 0.f};
    }

    float* o = out + (size_t)b0 * N + n0 + lane;
    o[0 * N] = p0.x;
    o[1 * N] = p1.x;
    o[2 * N] = p2.x;
    o[3 * N] = p3.x;
    o[4 * N] = p4.x;
    o[5 * N] = p5.x;
    o[6 * N] = p6.x;
    o[7 * N] = p7.x;
}

extern "C" void kernel_launch(void* const* d_in, const int* in_sizes, int n_in,
                              void* d_out, int out_size, void* d_ws, size_t ws_size,
                              hipStream_t stream)
{
    const float* x     = (const float*)d_in[0];
    const float* bias  = (const float*)d_in[1];
    const float* scale = (const float*)d_in[2];
    float* out = (float*)d_out;

    const int B = in_sizes[0] / DD;   // 2048
    const int N = in_sizes[1] / DD;   // 512

    dim3 grid(N / 64, B / 64);        // (8, 32) = 256 blocks = 1 per CU
    wavelet_prod_kernel<<<grid, 512, 0, stream>>>(x, bias, scale, out, B, N);
}